// Round 5
// baseline (20640.182 us; speedup 1.0000x reference)
//
#include <hip/hip_runtime.h>

// VectorQuantizer: z [8192,1024] f32, embed [4096,256] f32
// outputs (flat f32): quantized_st [8388608], indices [32768], loss, codebook_loss, commitment_loss, perplexity

constexpr int D_CODE  = 256;
constexpr int M_ROWS  = 32768;       // 8192*4
constexpr int K_EMB   = 4096;
constexpr long Q_ELEMS = 8388608L;   // 8192*1024

typedef float v2f __attribute__((ext_vector_type(2)));

// workspace layout (bytes)
constexpr size_t OFF_SUMZ = 0;         // 32768 f32  (128 KB)
constexpr size_t OFF_SUME = 131072;    // 4096 f32   (16 KB)
constexpr size_t OFF_BEST = 147456;    // 32768 u64  (256 KB)
constexpr size_t OFF_IDX  = 409600;    // 32768 i32  (128 KB)
constexpr size_t OFF_HIST = 540672;    // 4096 u32   (16 KB)
constexpr size_t OFF_DACC = 557056;    // 1 double
constexpr size_t ZERO_LEN = 16392;     // hist + dacc (contiguous)

__device__ __forceinline__ unsigned long long umin64(unsigned long long a, unsigned long long b) {
  return a < b ? a : b;
}

// ---------------- kernel 1: row sums of squares (z and embed) ----------------
__global__ __launch_bounds__(256) void k_rowsums(const float* __restrict__ z,
                                                 const float* __restrict__ emb,
                                                 float* __restrict__ sumz,
                                                 float* __restrict__ sume) {
  int w = threadIdx.x >> 6, lane = threadIdx.x & 63;
  int row = blockIdx.x * 4 + w;                  // 0..36863
  const float* src;
  float* dst;
  if (row < M_ROWS) { src = z + (size_t)row * D_CODE; dst = sumz + row; }
  else              { src = emb + (size_t)(row - M_ROWS) * D_CODE; dst = sume + (row - M_ROWS); }
  float4 v = *(const float4*)(src + lane * 4);
  float s = (v.x * v.x + v.y * v.y) + (v.z * v.z + v.w * v.w);
  #pragma unroll
  for (int off = 32; off; off >>= 1) s += __shfl_xor(s, off, 64);
  if (lane == 0) *dst = s;
}

// ---------------- kernel 2: fused fp32 distance + argmin ----------------
// Block = 64 rows x 128 cands, 256 thr = 4 waves. Wave w owns cands c0+w*32..+31;
// all waves share the same 64 rows. Per thread: 8 rows (ly=lane>>3) x 4 cands (tx=lane&7).
// z: global float4 per (row, 4k) — per-CU footprint 4 blk x 64 rows x 128B = 32KB = L1,
//    so each row's 128B line is L1-resident across the 8 kq steps of a kk-phase.
// e: LDS k-pair layout ebuf[buf][kp][c] (float2 = codes' k,k+1 for cand c):
//    one b128 read = 2 cands x 2 k = exactly the v_pk_fma operands; 8-way tx-broadcast,
//    2-way banks. Double-buffered, issue-early/write-late staging (T14), 1 barrier/phase.
// acc: v2f per (row,cand) = even/odd-k partial sums (R2-proven order), 64 f32 total.
// Grid 16384 = 32 q x 512 rt, bid = q*512+rt -> XCD = rt%8: q-siblings co-XCD (z slice 4MB = L2).
__global__ __launch_bounds__(256, 4) void k_argmin(const float* __restrict__ z,
                                                   const float* __restrict__ emb,
                                                   const float* __restrict__ sumz,
                                                   const float* __restrict__ sume,
                                                   unsigned long long* __restrict__ best64) {
  __shared__ float2 ebuf[2][16][130];             // 2 x 16 kp x (128 cands + pad) = 33.3 KB

  const int tid  = threadIdx.x;
  const int w    = tid >> 6;                      // wave 0..3
  const int lane = tid & 63;
  const int tx   = lane & 7;
  const int ly   = lane >> 3;
  const int rt   = blockIdx.x & 511;
  const int q    = blockIdx.x >> 9;               // 0..31
  const int row0 = rt * 64 + ly * 8;              // this thread's first row
  const int c0   = q * 128;

  const float* zb = z + (size_t)row0 * D_CODE;
  const int cb = w * 32 + tx * 4;                 // cand offset within tile (float2 index = cand)

  v2f acc[8][4];
  #pragma unroll
  for (int i = 0; i < 8; ++i)
    #pragma unroll
    for (int j = 0; j < 4; ++j) acc[i][j] = (v2f)(0.0f);

  // staging decomposition: thread t loads cand sc = t&127, k-half sh = t>>7 (16 k each)
  const int sc = tid & 127;
  const int sh = tid >> 7;
  const float* esrc = emb + (size_t)(c0 + sc) * D_CODE + sh * 16;

  float4 st[4];
  #pragma unroll
  for (int p = 0; p < 4; ++p) st[p] = *(const float4*)(esrc + p * 4);   // kk=0
  #pragma unroll
  for (int p = 0; p < 4; ++p) {
    int kp = sh * 8 + 2 * p;
    ebuf[0][kp][sc]     = (float2){st[p].x, st[p].y};
    ebuf[0][kp + 1][sc] = (float2){st[p].z, st[p].w};
  }
  __syncthreads();

  #pragma unroll 1
  for (int kk = 0; kk < 8; ++kk) {
    const int b = kk & 1;
    // T14: issue next phase's global loads before compute
    if (kk < 7) {
      #pragma unroll
      for (int p = 0; p < 4; ++p) st[p] = *(const float4*)(esrc + (kk + 1) * 32 + p * 4);
    }

    // compute this phase: 32 k as 8 kq-steps of 4 k
    #pragma unroll
    for (int kq = 0; kq < 8; ++kq) {
      const int kp0 = 2 * kq;
      float4 e0 = *(const float4*)&ebuf[b][kp0][cb];          // cands cb,cb+1 @ k-pair kp0
      float4 e1 = *(const float4*)&ebuf[b][kp0][cb + 2];      // cands cb+2,cb+3
      float4 e2 = *(const float4*)&ebuf[b][kp0 + 1][cb];
      float4 e3 = *(const float4*)&ebuf[b][kp0 + 1][cb + 2];
      #pragma unroll
      for (int i = 0; i < 8; ++i) {
        float4 zv = *(const float4*)(zb + (size_t)i * D_CODE + kk * 32 + kq * 4);
        v2f za = (v2f){zv.x, zv.y};                           // k-pair kp0
        v2f zc = (v2f){zv.z, zv.w};                           // k-pair kp0+1
        acc[i][0] = __builtin_elementwise_fma(za, (v2f){e0.x, e0.y}, acc[i][0]);
        acc[i][1] = __builtin_elementwise_fma(za, (v2f){e0.z, e0.w}, acc[i][1]);
        acc[i][2] = __builtin_elementwise_fma(za, (v2f){e1.x, e1.y}, acc[i][2]);
        acc[i][3] = __builtin_elementwise_fma(za, (v2f){e1.z, e1.w}, acc[i][3]);
        acc[i][0] = __builtin_elementwise_fma(zc, (v2f){e2.x, e2.y}, acc[i][0]);
        acc[i][1] = __builtin_elementwise_fma(zc, (v2f){e2.z, e2.w}, acc[i][1]);
        acc[i][2] = __builtin_elementwise_fma(zc, (v2f){e3.x, e3.y}, acc[i][2]);
        acc[i][3] = __builtin_elementwise_fma(zc, (v2f){e3.z, e3.w}, acc[i][3]);
      }
    }

    // write-late: store prefetched tile into the other buffer, then one barrier
    if (kk < 7) {
      #pragma unroll
      for (int p = 0; p < 4; ++p) {
        int kp = sh * 8 + 2 * p;
        ebuf[b ^ 1][kp][sc]     = (float2){st[p].x, st[p].y};
        ebuf[b ^ 1][kp + 1][sc] = (float2){st[p].z, st[p].w};
      }
      __syncthreads();
    }
  }

  // epilogue: literal fp32 distance d = (sumz - 2*dot) + sume, first-index tie-break
  float sz[8];
  #pragma unroll
  for (int i = 0; i < 8; ++i) sz[i] = sumz[row0 + i];
  unsigned long long bestRow[8];
  #pragma unroll
  for (int i = 0; i < 8; ++i) bestRow[i] = ~0ULL;
  #pragma unroll
  for (int j = 0; j < 4; ++j) {
    int cg = c0 + cb + j;
    float se = sume[cg];
    #pragma unroll
    for (int i = 0; i < 8; ++i) {
      float dot = acc[i][j].x + acc[i][j].y;      // even + odd partials (R2-proven, absmax 0)
      float dd = (sz[i] - 2.0f * dot) + se;       // same roundings as the reference
      unsigned long long key =
          ((unsigned long long)__float_as_uint(dd) << 32) | (unsigned int)cg;
      bestRow[i] = umin64(bestRow[i], key);
    }
  }
  #pragma unroll
  for (int i = 0; i < 8; ++i) {
    unsigned long long bv = bestRow[i];
    bv = umin64(bv, __shfl_xor(bv, 1, 8));
    bv = umin64(bv, __shfl_xor(bv, 2, 8));
    bv = umin64(bv, __shfl_xor(bv, 4, 8));
    if (tx == 0) atomicMin(&best64[row0 + i], bv);
  }
}

// ---------------- kernel 3: emit indices + histogram ----------------
__global__ __launch_bounds__(256) void k_merge(const unsigned long long* __restrict__ best64,
                                               int* __restrict__ idx,
                                               float* __restrict__ outI,
                                               unsigned int* __restrict__ hist) {
  int r = blockIdx.x * 256 + threadIdx.x;
  unsigned long long b = best64[r];
  int id = (int)(unsigned int)(b & 0xffffffffULL);
  idx[r] = id;
  outI[r] = (float)id;
  atomicAdd(&hist[id], 1u);
}

// ---------------- kernel 4: quantized_st (bit-exact) + commitment accumulator ----------------
__global__ __launch_bounds__(256) void k_quant(const float* __restrict__ z,
                                               const float* __restrict__ emb,
                                               const int* __restrict__ idx,
                                               float* __restrict__ outQ,
                                               double* __restrict__ dacc) {
  __shared__ double sd[256];
  const long NF4 = Q_ELEMS / 4;                    // 2097152 float4
  long f0 = (long)blockIdx.x * 256 + threadIdx.x;  // 524288 threads
  double s = 0.0;
  for (long f = f0; f < NF4; f += 524288) {
    long m = f >> 6;                               // flat_z row
    int d4 = (int)(f & 63) * 4;
    int id = idx[m];
    float4 zv = *(const float4*)(z + f * 4);
    float4 qv = *(const float4*)(emb + (size_t)id * D_CODE + d4);
    float dx = qv.x - zv.x, dy = qv.y - zv.y, dz = qv.z - zv.z, dw = qv.w - zv.w;
    float4 ov;
    ov.x = zv.x + dx; ov.y = zv.y + dy; ov.z = zv.z + dz; ov.w = zv.w + dw;  // z + (q - z), literal
    *(float4*)(outQ + f * 4) = ov;
    s += (double)dx * (double)dx + (double)dy * (double)dy
       + (double)dz * (double)dz + (double)dw * (double)dw;
  }
  sd[threadIdx.x] = s;
  __syncthreads();
  #pragma unroll
  for (int o = 128; o; o >>= 1) {
    if (threadIdx.x < o) sd[threadIdx.x] += sd[threadIdx.x + o];
    __syncthreads();
  }
  if (threadIdx.x == 0) atomicAdd(dacc, sd[0]);
}

// ---------------- kernel 5: scalars ----------------
__global__ __launch_bounds__(256) void k_final(const unsigned int* __restrict__ hist,
                                               const double* __restrict__ dacc,
                                               float* __restrict__ outS) {
  __shared__ double sd[256];
  double s = 0.0;
  for (int c = threadIdx.x; c < K_EMB; c += 256) {
    double p = (double)hist[c] * (1.0 / 32768.0);
    s += p * log(p + 1e-10);
  }
  sd[threadIdx.x] = s;
  __syncthreads();
  #pragma unroll
  for (int o = 128; o; o >>= 1) {
    if (threadIdx.x < o) sd[threadIdx.x] += sd[threadIdx.x + o];
    __syncthreads();
  }
  if (threadIdx.x == 0) {
    float commit = (float)(dacc[0] / (double)Q_ELEMS);
    outS[0] = 0.25f * commit;   // loss = 1.0*0 + 0.25*commitment
    outS[1] = 0.0f;             // codebook_loss (EMA eval mode)
    outS[2] = commit;           // commitment_loss
    outS[3] = (float)exp(-sd[0]);  // perplexity
  }
}

extern "C" void kernel_launch(void* const* d_in, const int* in_sizes, int n_in,
                              void* d_out, int out_size, void* d_ws, size_t ws_size,
                              hipStream_t stream) {
  const float* z   = (const float*)d_in[0];
  const float* emb = (const float*)d_in[1];
  float* out = (float*)d_out;
  char* ws = (char*)d_ws;

  float* sumz = (float*)(ws + OFF_SUMZ);
  float* sume = (float*)(ws + OFF_SUME);
  unsigned long long* best64 = (unsigned long long*)(ws + OFF_BEST);
  int* idx = (int*)(ws + OFF_IDX);
  unsigned int* hist = (unsigned int*)(ws + OFF_HIST);
  double* dacc = (double*)(ws + OFF_DACC);

  hipMemsetAsync(ws + OFF_HIST, 0, ZERO_LEN, stream);    // hist + dacc
  hipMemsetAsync(ws + OFF_BEST, 0xFF, 262144, stream);   // best64 = ~0

  k_rowsums<<<9216, 256, 0, stream>>>(z, emb, sumz, sume);
  k_argmin<<<16384, 256, 0, stream>>>(z, emb, sumz, sume, best64);
  k_merge<<<M_ROWS / 256, 256, 0, stream>>>(best64, idx, out + Q_ELEMS, hist);
  k_quant<<<2048, 256, 0, stream>>>(z, emb, idx, out, dacc);
  k_final<<<1, 256, 0, stream>>>(hist, dacc, out + Q_ELEMS + M_ROWS);
}

// Round 7
// 2245.009 us; speedup vs baseline: 9.1938x; 9.1938x over previous
//
#include <hip/hip_runtime.h>

// VectorQuantizer: z [8192,1024] f32, embed [4096,256] f32
// outputs (flat f32): quantized_st [8388608], indices [32768], loss, codebook_loss, commitment_loss, perplexity

constexpr int D_CODE  = 256;
constexpr int M_ROWS  = 32768;       // 8192*4
constexpr int K_EMB   = 4096;
constexpr long Q_ELEMS = 8388608L;   // 8192*1024

typedef float v2f __attribute__((ext_vector_type(2)));

// workspace layout (bytes)
constexpr size_t OFF_SUMZ = 0;         // 32768 f32  (128 KB)
constexpr size_t OFF_SUME = 131072;    // 4096 f32   (16 KB)
constexpr size_t OFF_BEST = 147456;    // 32768 u64  (256 KB)
constexpr size_t OFF_IDX  = 409600;    // 32768 i32  (128 KB)
constexpr size_t OFF_HIST = 540672;    // 4096 u32   (16 KB)
constexpr size_t OFF_DACC = 557056;    // 1 double
constexpr size_t ZERO_LEN = 16392;     // hist + dacc (contiguous)

__device__ __forceinline__ unsigned long long umin64(unsigned long long a, unsigned long long b) {
  return a < b ? a : b;
}

// ---------------- kernel 1: row sums of squares (z and embed) ----------------
__global__ __launch_bounds__(256) void k_rowsums(const float* __restrict__ z,
                                                 const float* __restrict__ emb,
                                                 float* __restrict__ sumz,
                                                 float* __restrict__ sume) {
  int w = threadIdx.x >> 6, lane = threadIdx.x & 63;
  int row = blockIdx.x * 4 + w;                  // 0..36863
  const float* src;
  float* dst;
  if (row < M_ROWS) { src = z + (size_t)row * D_CODE; dst = sumz + row; }
  else              { src = emb + (size_t)(row - M_ROWS) * D_CODE; dst = sume + (row - M_ROWS); }
  float4 v = *(const float4*)(src + lane * 4);
  float s = (v.x * v.x + v.y * v.y) + (v.z * v.z + v.w * v.w);
  #pragma unroll
  for (int off = 32; off; off >>= 1) s += __shfl_xor(s, off, 64);
  if (lane == 0) *dst = s;
}

// ---------------- kernel 2: fused fp32 distance + argmin ----------------
// Block = 64 rows x 128 cands, 256 thr = 4 waves. Wave w owns cands c0+w*32..+31;
// all waves share the same 64 rows. Per thread: 8 rows (ly=lane>>3) x 4 cands (tx=lane&7).
// z: global float4 per (row, 4k) — per-CU footprint ~3 blk x 64 rows x 128B = 24KB < L1,
//    so each row's 128B line is L1-resident across the 8 kq steps of a kk-phase.
// e: LDS k-pair layout ebuf[buf][kp][c] (float2 = codes' k,k+1 for cand c):
//    one b128 read = 2 cands x 2 k = exactly the v_pk_fma operands; 8-way tx-broadcast,
//    2-way banks. Double-buffered, issue-early/write-late staging (T14), 1 barrier/phase.
// acc: v2f per (row,cand) = even/odd-k partial sums (R2-proven order), 64 f32 total.
// NO min-waves launch bound: empirically __launch_bounds__(256,w) caps VGPR at ~512/(2w)
// (R1/R3/R5: 2->128, 3->84, 4->64) and R5's cap-64 spilled acc to scratch (46.9 GB WRITE,
// 20.7 ms). Let the compiler allocate (~130-170) -> zero spill, ~3 blocks/CU.
// Grid 16384 = 32 q x 512 rt, bid = q*512+rt -> XCD = rt%8: q-siblings co-XCD (z slice 4MB = L2).
__global__ __launch_bounds__(256) void k_argmin(const float* __restrict__ z,
                                                const float* __restrict__ emb,
                                                const float* __restrict__ sumz,
                                                const float* __restrict__ sume,
                                                unsigned long long* __restrict__ best64) {
  __shared__ float2 ebuf[2][16][130];             // 2 x 16 kp x (128 cands + pad) = 33.3 KB

  const int tid  = threadIdx.x;
  const int w    = tid >> 6;                      // wave 0..3
  const int lane = tid & 63;
  const int tx   = lane & 7;
  const int ly   = lane >> 3;
  const int rt   = blockIdx.x & 511;
  const int q    = blockIdx.x >> 9;               // 0..31
  const int row0 = rt * 64 + ly * 8;              // this thread's first row
  const int c0   = q * 128;

  const float* zb = z + (size_t)row0 * D_CODE;
  const int cb = w * 32 + tx * 4;                 // cand offset within tile (float2 index = cand)

  v2f acc[8][4];
  #pragma unroll
  for (int i = 0; i < 8; ++i)
    #pragma unroll
    for (int j = 0; j < 4; ++j) acc[i][j] = (v2f)(0.0f);

  // staging decomposition: thread t loads cand sc = t&127, k-half sh = t>>7 (16 k each)
  const int sc = tid & 127;
  const int sh = tid >> 7;
  const float* esrc = emb + (size_t)(c0 + sc) * D_CODE + sh * 16;

  float4 st[4];
  #pragma unroll
  for (int p = 0; p < 4; ++p) st[p] = *(const float4*)(esrc + p * 4);   // kk=0
  #pragma unroll
  for (int p = 0; p < 4; ++p) {
    int kp = sh * 8 + 2 * p;
    ebuf[0][kp][sc]     = (float2){st[p].x, st[p].y};
    ebuf[0][kp + 1][sc] = (float2){st[p].z, st[p].w};
  }
  __syncthreads();

  #pragma unroll 1
  for (int kk = 0; kk < 8; ++kk) {
    const int b = kk & 1;
    // T14: issue next phase's global loads before compute
    if (kk < 7) {
      #pragma unroll
      for (int p = 0; p < 4; ++p) st[p] = *(const float4*)(esrc + (kk + 1) * 32 + p * 4);
    }

    // compute this phase: 32 k as 8 kq-steps of 4 k
    #pragma unroll
    for (int kq = 0; kq < 8; ++kq) {
      const int kp0 = 2 * kq;
      float4 e0 = *(const float4*)&ebuf[b][kp0][cb];          // cands cb,cb+1 @ k-pair kp0
      float4 e1 = *(const float4*)&ebuf[b][kp0][cb + 2];      // cands cb+2,cb+3
      float4 e2 = *(const float4*)&ebuf[b][kp0 + 1][cb];
      float4 e3 = *(const float4*)&ebuf[b][kp0 + 1][cb + 2];
      #pragma unroll
      for (int i = 0; i < 8; ++i) {
        float4 zv = *(const float4*)(zb + (size_t)i * D_CODE + kk * 32 + kq * 4);
        v2f za = (v2f){zv.x, zv.y};                           // k-pair kp0
        v2f zc = (v2f){zv.z, zv.w};                           // k-pair kp0+1
        acc[i][0] = __builtin_elementwise_fma(za, (v2f){e0.x, e0.y}, acc[i][0]);
        acc[i][1] = __builtin_elementwise_fma(za, (v2f){e0.z, e0.w}, acc[i][1]);
        acc[i][2] = __builtin_elementwise_fma(za, (v2f){e1.x, e1.y}, acc[i][2]);
        acc[i][3] = __builtin_elementwise_fma(za, (v2f){e1.z, e1.w}, acc[i][3]);
        acc[i][0] = __builtin_elementwise_fma(zc, (v2f){e2.x, e2.y}, acc[i][0]);
        acc[i][1] = __builtin_elementwise_fma(zc, (v2f){e2.z, e2.w}, acc[i][1]);
        acc[i][2] = __builtin_elementwise_fma(zc, (v2f){e3.x, e3.y}, acc[i][2]);
        acc[i][3] = __builtin_elementwise_fma(zc, (v2f){e3.z, e3.w}, acc[i][3]);
      }
    }

    // write-late: store prefetched tile into the other buffer, then one barrier
    if (kk < 7) {
      #pragma unroll
      for (int p = 0; p < 4; ++p) {
        int kp = sh * 8 + 2 * p;
        ebuf[b ^ 1][kp][sc]     = (float2){st[p].x, st[p].y};
        ebuf[b ^ 1][kp + 1][sc] = (float2){st[p].z, st[p].w};
      }
      __syncthreads();
    }
  }

  // epilogue: literal fp32 distance d = (sumz - 2*dot) + sume, first-index tie-break
  float sz[8];
  #pragma unroll
  for (int i = 0; i < 8; ++i) sz[i] = sumz[row0 + i];
  unsigned long long bestRow[8];
  #pragma unroll
  for (int i = 0; i < 8; ++i) bestRow[i] = ~0ULL;
  #pragma unroll
  for (int j = 0; j < 4; ++j) {
    int cg = c0 + cb + j;
    float se = sume[cg];
    #pragma unroll
    for (int i = 0; i < 8; ++i) {
      float dot = acc[i][j].x + acc[i][j].y;      // even + odd partials (R2-proven, absmax 0)
      float dd = (sz[i] - 2.0f * dot) + se;       // same roundings as the reference
      unsigned long long key =
          ((unsigned long long)__float_as_uint(dd) << 32) | (unsigned int)cg;
      bestRow[i] = umin64(bestRow[i], key);
    }
  }
  #pragma unroll
  for (int i = 0; i < 8; ++i) {
    unsigned long long bv = bestRow[i];
    bv = umin64(bv, __shfl_xor(bv, 1, 8));
    bv = umin64(bv, __shfl_xor(bv, 2, 8));
    bv = umin64(bv, __shfl_xor(bv, 4, 8));
    if (tx == 0) atomicMin(&best64[row0 + i], bv);
  }
}

// ---------------- kernel 3: emit indices + histogram ----------------
__global__ __launch_bounds__(256) void k_merge(const unsigned long long* __restrict__ best64,
                                               int* __restrict__ idx,
                                               float* __restrict__ outI,
                                               unsigned int* __restrict__ hist) {
  int r = blockIdx.x * 256 + threadIdx.x;
  unsigned long long b = best64[r];
  int id = (int)(unsigned int)(b & 0xffffffffULL);
  idx[r] = id;
  outI[r] = (float)id;
  atomicAdd(&hist[id], 1u);
}

// ---------------- kernel 4: quantized_st (bit-exact) + commitment accumulator ----------------
__global__ __launch_bounds__(256) void k_quant(const float* __restrict__ z,
                                               const float* __restrict__ emb,
                                               const int* __restrict__ idx,
                                               float* __restrict__ outQ,
                                               double* __restrict__ dacc) {
  __shared__ double sd[256];
  const long NF4 = Q_ELEMS / 4;                    // 2097152 float4
  long f0 = (long)blockIdx.x * 256 + threadIdx.x;  // 524288 threads
  double s = 0.0;
  for (long f = f0; f < NF4; f += 524288) {
    long m = f >> 6;                               // flat_z row
    int d4 = (int)(f & 63) * 4;
    int id = idx[m];
    float4 zv = *(const float4*)(z + f * 4);
    float4 qv = *(const float4*)(emb + (size_t)id * D_CODE + d4);
    float dx = qv.x - zv.x, dy = qv.y - zv.y, dz = qv.z - zv.z, dw = qv.w - zv.w;
    float4 ov;
    ov.x = zv.x + dx; ov.y = zv.y + dy; ov.z = zv.z + dz; ov.w = zv.w + dw;  // z + (q - z), literal
    *(float4*)(outQ + f * 4) = ov;
    s += (double)dx * (double)dx + (double)dy * (double)dy
       + (double)dz * (double)dz + (double)dw * (double)dw;
  }
  sd[threadIdx.x] = s;
  __syncthreads();
  #pragma unroll
  for (int o = 128; o; o >>= 1) {
    if (threadIdx.x < o) sd[threadIdx.x] += sd[threadIdx.x + o];
    __syncthreads();
  }
  if (threadIdx.x == 0) atomicAdd(dacc, sd[0]);
}

// ---------------- kernel 5: scalars ----------------
__global__ __launch_bounds__(256) void k_final(const unsigned int* __restrict__ hist,
                                               const double* __restrict__ dacc,
                                               float* __restrict__ outS) {
  __shared__ double sd[256];
  double s = 0.0;
  for (int c = threadIdx.x; c < K_EMB; c += 256) {
    double p = (double)hist[c] * (1.0 / 32768.0);
    s += p * log(p + 1e-10);
  }
  sd[threadIdx.x] = s;
  __syncthreads();
  #pragma unroll
  for (int o = 128; o; o >>= 1) {
    if (threadIdx.x < o) sd[threadIdx.x] += sd[threadIdx.x + o];
    __syncthreads();
  }
  if (threadIdx.x == 0) {
    float commit = (float)(dacc[0] / (double)Q_ELEMS);
    outS[0] = 0.25f * commit;   // loss = 1.0*0 + 0.25*commitment
    outS[1] = 0.0f;             // codebook_loss (EMA eval mode)
    outS[2] = commit;           // commitment_loss
    outS[3] = (float)exp(-sd[0]);  // perplexity
  }
}

extern "C" void kernel_launch(void* const* d_in, const int* in_sizes, int n_in,
                              void* d_out, int out_size, void* d_ws, size_t ws_size,
                              hipStream_t stream) {
  const float* z   = (const float*)d_in[0];
  const float* emb = (const float*)d_in[1];
  float* out = (float*)d_out;
  char* ws = (char*)d_ws;

  float* sumz = (float*)(ws + OFF_SUMZ);
  float* sume = (float*)(ws + OFF_SUME);
  unsigned long long* best64 = (unsigned long long*)(ws + OFF_BEST);
  int* idx = (int*)(ws + OFF_IDX);
  unsigned int* hist = (unsigned int*)(ws + OFF_HIST);
  double* dacc = (double*)(ws + OFF_DACC);

  hipMemsetAsync(ws + OFF_HIST, 0, ZERO_LEN, stream);    // hist + dacc
  hipMemsetAsync(ws + OFF_BEST, 0xFF, 262144, stream);   // best64 = ~0

  k_rowsums<<<9216, 256, 0, stream>>>(z, emb, sumz, sume);
  k_argmin<<<16384, 256, 0, stream>>>(z, emb, sumz, sume, best64);
  k_merge<<<M_ROWS / 256, 256, 0, stream>>>(best64, idx, out + Q_ELEMS, hist);
  k_quant<<<2048, 256, 0, stream>>>(z, emb, idx, out, dacc);
  k_final<<<1, 256, 0, stream>>>(hist, dacc, out + Q_ELEMS + M_ROWS);
}

// Round 8
// 1345.597 us; speedup vs baseline: 15.3390x; 1.6684x over previous
//
#include <hip/hip_runtime.h>

// VectorQuantizer: z [8192,1024] f32, embed [4096,256] f32
// outputs (flat f32): quantized_st [8388608], indices [32768], loss, codebook_loss, commitment_loss, perplexity

constexpr int D_CODE  = 256;
constexpr int M_ROWS  = 32768;       // 8192*4
constexpr int K_EMB   = 4096;
constexpr long Q_ELEMS = 8388608L;   // 8192*1024

typedef float v2f __attribute__((ext_vector_type(2)));

// workspace layout (bytes)
constexpr size_t OFF_SUMZ = 0;         // 32768 f32  (128 KB)
constexpr size_t OFF_SUME = 131072;    // 4096 f32   (16 KB)
constexpr size_t OFF_BEST = 147456;    // 32768 u64  (256 KB)
constexpr size_t OFF_IDX  = 409600;    // 32768 i32  (128 KB)
constexpr size_t OFF_HIST = 540672;    // 4096 u32   (16 KB)
constexpr size_t OFF_DACC = 557056;    // 1 double
constexpr size_t ZERO_LEN = 16392;     // hist + dacc (contiguous)

__device__ __forceinline__ unsigned long long umin64(unsigned long long a, unsigned long long b) {
  return a < b ? a : b;
}

// ---------------- kernel 1: row sums of squares (z and embed) ----------------
__global__ __launch_bounds__(256) void k_rowsums(const float* __restrict__ z,
                                                 const float* __restrict__ emb,
                                                 float* __restrict__ sumz,
                                                 float* __restrict__ sume) {
  int w = threadIdx.x >> 6, lane = threadIdx.x & 63;
  int row = blockIdx.x * 4 + w;                  // 0..36863
  const float* src;
  float* dst;
  if (row < M_ROWS) { src = z + (size_t)row * D_CODE; dst = sumz + row; }
  else              { src = emb + (size_t)(row - M_ROWS) * D_CODE; dst = sume + (row - M_ROWS); }
  float4 v = *(const float4*)(src + lane * 4);
  float s = (v.x * v.x + v.y * v.y) + (v.z * v.z + v.w * v.w);
  #pragma unroll
  for (int off = 32; off; off >>= 1) s += __shfl_xor(s, off, 64);
  if (lane == 0) *dst = s;
}

// ---------------- kernel 2: fused fp32 distance + argmin ----------------
// Block = 64 rows x 128 cands, 256 thr = 4 waves. Per thread: 8 rows x 4 cands (v2f acc,
// even/odd-k pairs -> v_pk_fma_f32; R2-proven order, absmax 0).
// z: global float4 per (row, 4k), L1-resident (per-CU footprint ~3 blk x 8KB = 24KB).
// e: LDS k-pair layout ebuf[buf][kp][c], double-buffered, T14 issue-early/write-late.
// R7 lesson: FULLY unrolling the kq loop let the scheduler hoist all 64 z-loads ->
// VGPR 240 -> ~1 block/CU (Occupancy 12%) -> latency-bound 2293us. Fix: #pragma unroll 2
// bounds the hoist window to 16 float4 -> target VGPR 140-170, 3 waves/SIMD.
// NO min-waves launch bound (R5: __launch_bounds__(256,4) caps VGPR at 64 -> 46.9GB spill).
// Grid 16384 = 32 q x 512 rt, bid = q*512+rt; consecutive co-resident blocks share q
// (same e-tile -> L2 hits); XCD = rt%8 keeps q-siblings of a row-tile co-XCD.
__global__ __launch_bounds__(256) void k_argmin(const float* __restrict__ z,
                                                const float* __restrict__ emb,
                                                const float* __restrict__ sumz,
                                                const float* __restrict__ sume,
                                                unsigned long long* __restrict__ best64) {
  __shared__ float2 ebuf[2][16][130];             // 2 x 16 kp x (128 cands + pad) = 33.3 KB

  const int tid  = threadIdx.x;
  const int w    = tid >> 6;                      // wave 0..3
  const int lane = tid & 63;
  const int tx   = lane & 7;
  const int ly   = lane >> 3;
  const int rt   = blockIdx.x & 511;
  const int q    = blockIdx.x >> 9;               // 0..31
  const int row0 = rt * 64 + ly * 8;              // this thread's first row
  const int c0   = q * 128;

  const float* zb = z + (size_t)row0 * D_CODE;
  const int cb = w * 32 + tx * 4;                 // cand offset within tile (float2 index = cand)

  v2f acc[8][4];
  #pragma unroll
  for (int i = 0; i < 8; ++i)
    #pragma unroll
    for (int j = 0; j < 4; ++j) acc[i][j] = (v2f)(0.0f);

  // staging decomposition: thread t loads cand sc = t&127, k-half sh = t>>7 (16 k each)
  const int sc = tid & 127;
  const int sh = tid >> 7;
  const float* esrc = emb + (size_t)(c0 + sc) * D_CODE + sh * 16;

  float4 st[4];
  #pragma unroll
  for (int p = 0; p < 4; ++p) st[p] = *(const float4*)(esrc + p * 4);   // kk=0
  #pragma unroll
  for (int p = 0; p < 4; ++p) {
    int kp = sh * 8 + 2 * p;
    ebuf[0][kp][sc]     = (float2){st[p].x, st[p].y};
    ebuf[0][kp + 1][sc] = (float2){st[p].z, st[p].w};
  }
  __syncthreads();

  #pragma unroll 1
  for (int kk = 0; kk < 8; ++kk) {
    const int b = kk & 1;
    // T14: issue next phase's global loads before compute
    if (kk < 7) {
      #pragma unroll
      for (int p = 0; p < 4; ++p) st[p] = *(const float4*)(esrc + (kk + 1) * 32 + p * 4);
    }

    // compute this phase: 32 k as 8 kq-steps of 4 k.
    // unroll 2 (NOT full): bounds the z-load hoist window -> VGPR under control (R7 lesson).
    #pragma unroll 2
    for (int kq = 0; kq < 8; ++kq) {
      const int kp0 = 2 * kq;
      float4 e0 = *(const float4*)&ebuf[b][kp0][cb];          // cands cb,cb+1 @ k-pair kp0
      float4 e1 = *(const float4*)&ebuf[b][kp0][cb + 2];      // cands cb+2,cb+3
      float4 e2 = *(const float4*)&ebuf[b][kp0 + 1][cb];
      float4 e3 = *(const float4*)&ebuf[b][kp0 + 1][cb + 2];
      #pragma unroll
      for (int i = 0; i < 8; ++i) {
        float4 zv = *(const float4*)(zb + (size_t)i * D_CODE + kk * 32 + kq * 4);
        v2f za = (v2f){zv.x, zv.y};                           // k-pair kp0
        v2f zc = (v2f){zv.z, zv.w};                           // k-pair kp0+1
        acc[i][0] = __builtin_elementwise_fma(za, (v2f){e0.x, e0.y}, acc[i][0]);
        acc[i][1] = __builtin_elementwise_fma(za, (v2f){e0.z, e0.w}, acc[i][1]);
        acc[i][2] = __builtin_elementwise_fma(za, (v2f){e1.x, e1.y}, acc[i][2]);
        acc[i][3] = __builtin_elementwise_fma(za, (v2f){e1.z, e1.w}, acc[i][3]);
        acc[i][0] = __builtin_elementwise_fma(zc, (v2f){e2.x, e2.y}, acc[i][0]);
        acc[i][1] = __builtin_elementwise_fma(zc, (v2f){e2.z, e2.w}, acc[i][1]);
        acc[i][2] = __builtin_elementwise_fma(zc, (v2f){e3.x, e3.y}, acc[i][2]);
        acc[i][3] = __builtin_elementwise_fma(zc, (v2f){e3.z, e3.w}, acc[i][3]);
      }
    }

    // write-late: store prefetched tile into the other buffer, then one barrier
    if (kk < 7) {
      #pragma unroll
      for (int p = 0; p < 4; ++p) {
        int kp = sh * 8 + 2 * p;
        ebuf[b ^ 1][kp][sc]     = (float2){st[p].x, st[p].y};
        ebuf[b ^ 1][kp + 1][sc] = (float2){st[p].z, st[p].w};
      }
      __syncthreads();
    }
  }

  // epilogue: literal fp32 distance d = (sumz - 2*dot) + sume, first-index tie-break
  float sz[8];
  #pragma unroll
  for (int i = 0; i < 8; ++i) sz[i] = sumz[row0 + i];
  unsigned long long bestRow[8];
  #pragma unroll
  for (int i = 0; i < 8; ++i) bestRow[i] = ~0ULL;
  #pragma unroll
  for (int j = 0; j < 4; ++j) {
    int cg = c0 + cb + j;
    float se = sume[cg];
    #pragma unroll
    for (int i = 0; i < 8; ++i) {
      float dot = acc[i][j].x + acc[i][j].y;      // even + odd partials (R2-proven, absmax 0)
      float dd = (sz[i] - 2.0f * dot) + se;       // same roundings as the reference
      unsigned long long key =
          ((unsigned long long)__float_as_uint(dd) << 32) | (unsigned int)cg;
      bestRow[i] = umin64(bestRow[i], key);
    }
  }
  #pragma unroll
  for (int i = 0; i < 8; ++i) {
    unsigned long long bv = bestRow[i];
    bv = umin64(bv, __shfl_xor(bv, 1, 8));
    bv = umin64(bv, __shfl_xor(bv, 2, 8));
    bv = umin64(bv, __shfl_xor(bv, 4, 8));
    if (tx == 0) atomicMin(&best64[row0 + i], bv);
  }
}

// ---------------- kernel 3: emit indices + histogram ----------------
__global__ __launch_bounds__(256) void k_merge(const unsigned long long* __restrict__ best64,
                                               int* __restrict__ idx,
                                               float* __restrict__ outI,
                                               unsigned int* __restrict__ hist) {
  int r = blockIdx.x * 256 + threadIdx.x;
  unsigned long long b = best64[r];
  int id = (int)(unsigned int)(b & 0xffffffffULL);
  idx[r] = id;
  outI[r] = (float)id;
  atomicAdd(&hist[id], 1u);
}

// ---------------- kernel 4: quantized_st (bit-exact) + commitment accumulator ----------------
__global__ __launch_bounds__(256) void k_quant(const float* __restrict__ z,
                                               const float* __restrict__ emb,
                                               const int* __restrict__ idx,
                                               float* __restrict__ outQ,
                                               double* __restrict__ dacc) {
  __shared__ double sd[256];
  const long NF4 = Q_ELEMS / 4;                    // 2097152 float4
  long f0 = (long)blockIdx.x * 256 + threadIdx.x;  // 524288 threads
  double s = 0.0;
  for (long f = f0; f < NF4; f += 524288) {
    long m = f >> 6;                               // flat_z row
    int d4 = (int)(f & 63) * 4;
    int id = idx[m];
    float4 zv = *(const float4*)(z + f * 4);
    float4 qv = *(const float4*)(emb + (size_t)id * D_CODE + d4);
    float dx = qv.x - zv.x, dy = qv.y - zv.y, dz = qv.z - zv.z, dw = qv.w - zv.w;
    float4 ov;
    ov.x = zv.x + dx; ov.y = zv.y + dy; ov.z = zv.z + dz; ov.w = zv.w + dw;  // z + (q - z), literal
    *(float4*)(outQ + f * 4) = ov;
    s += (double)dx * (double)dx + (double)dy * (double)dy
       + (double)dz * (double)dz + (double)dw * (double)dw;
  }
  sd[threadIdx.x] = s;
  __syncthreads();
  #pragma unroll
  for (int o = 128; o; o >>= 1) {
    if (threadIdx.x < o) sd[threadIdx.x] += sd[threadIdx.x + o];
    __syncthreads();
  }
  if (threadIdx.x == 0) atomicAdd(dacc, sd[0]);
}

// ---------------- kernel 5: scalars ----------------
__global__ __launch_bounds__(256) void k_final(const unsigned int* __restrict__ hist,
                                               const double* __restrict__ dacc,
                                               float* __restrict__ outS) {
  __shared__ double sd[256];
  double s = 0.0;
  for (int c = threadIdx.x; c < K_EMB; c += 256) {
    double p = (double)hist[c] * (1.0 / 32768.0);
    s += p * log(p + 1e-10);
  }
  sd[threadIdx.x] = s;
  __syncthreads();
  #pragma unroll
  for (int o = 128; o; o >>= 1) {
    if (threadIdx.x < o) sd[threadIdx.x] += sd[threadIdx.x + o];
    __syncthreads();
  }
  if (threadIdx.x == 0) {
    float commit = (float)(dacc[0] / (double)Q_ELEMS);
    outS[0] = 0.25f * commit;   // loss = 1.0*0 + 0.25*commitment
    outS[1] = 0.0f;             // codebook_loss (EMA eval mode)
    outS[2] = commit;           // commitment_loss
    outS[3] = (float)exp(-sd[0]);  // perplexity
  }
}

extern "C" void kernel_launch(void* const* d_in, const int* in_sizes, int n_in,
                              void* d_out, int out_size, void* d_ws, size_t ws_size,
                              hipStream_t stream) {
  const float* z   = (const float*)d_in[0];
  const float* emb = (const float*)d_in[1];
  float* out = (float*)d_out;
  char* ws = (char*)d_ws;

  float* sumz = (float*)(ws + OFF_SUMZ);
  float* sume = (float*)(ws + OFF_SUME);
  unsigned long long* best64 = (unsigned long long*)(ws + OFF_BEST);
  int* idx = (int*)(ws + OFF_IDX);
  unsigned int* hist = (unsigned int*)(ws + OFF_HIST);
  double* dacc = (double*)(ws + OFF_DACC);

  hipMemsetAsync(ws + OFF_HIST, 0, ZERO_LEN, stream);    // hist + dacc
  hipMemsetAsync(ws + OFF_BEST, 0xFF, 262144, stream);   // best64 = ~0

  k_rowsums<<<9216, 256, 0, stream>>>(z, emb, sumz, sume);
  k_argmin<<<16384, 256, 0, stream>>>(z, emb, sumz, sume, best64);
  k_merge<<<M_ROWS / 256, 256, 0, stream>>>(best64, idx, out + Q_ELEMS, hist);
  k_quant<<<2048, 256, 0, stream>>>(z, emb, idx, out, dacc);
  k_final<<<1, 256, 0, stream>>>(hist, dacc, out + Q_ELEMS + M_ROWS);
}